// Round 6
// baseline (6396.059 us; speedup 1.0000x reference)
//
#include <hip/hip_runtime.h>

typedef __attribute__((ext_vector_type(8))) short short8b;
typedef __attribute__((ext_vector_type(4))) float f32x4;

#define B_   32
#define T_   512
#define I_   1024
#define H_   1024
#define K_   2048          // I + H
#define NB   256           // blocks, each owns 4 H-cols (16 gate cols); 1 per CU
#define NTHR 128           // 2 waves: wave m handles batch rows m*16..m*16+15
#define BH   (B_ * H_)
#define HLAST (B_ * H_)
#define TBH ((long)T_ * B_ * H_)
#define SC_SYS __HIP_MEMORY_SCOPE_SYSTEM

__device__ __forceinline__ unsigned short f2bf(float f) {
  union { float f; unsigned u; } c; c.f = f;
  unsigned r = (c.u + 0x7FFFu + ((c.u >> 16) & 1u)) >> 16;  // RNE
  return (unsigned short)r;
}

__device__ __forceinline__ float sig_(float x)  { return 1.0f / (1.0f + __expf(-x)); }
__device__ __forceinline__ float tanh_(float x) { return 1.0f - 2.0f / (__expf(2.0f * x) + 1.0f); }

// x [B][T][I] f32  ->  xb [T][B][I] bf16 (step-t slab contiguous)
__global__ void convert_x_kernel(const float* __restrict__ x, unsigned short* __restrict__ xb) {
  long vid = (long)blockIdx.x * blockDim.x + threadIdx.x;
  long o = vid * 4;
  if (o >= (long)T_ * B_ * I_) return;
  int i  = (int)(o & (I_ - 1));
  long bt = o >> 10;
  int b  = (int)(bt & (B_ - 1));
  int t  = (int)(bt >> 5);
  float4 v = *reinterpret_cast<const float4*>(x + (((long)b * T_ + t) << 10) + i);
  ushort4 pk;
  pk.x = f2bf(v.x); pk.y = f2bf(v.y); pk.z = f2bf(v.z); pk.w = f2bf(v.w);
  *reinterpret_cast<ushort4*>(xb + o) = pk;
}

// ---- tagged-h helpers: dword = bf16 value (lo16) | epoch (hi16) ----
// Seqlock: a matching tag in the SAME dword guarantees freshness; no
// cross-location ordering assumptions. Stale reads simply retry.

__device__ __forceinline__ void ld_frag8(const unsigned* p, unsigned long long* u) {
  #pragma unroll
  for (int j = 0; j < 4; ++j)
    u[j] = __hip_atomic_load(reinterpret_cast<const unsigned long long*>(p) + j,
                             __ATOMIC_RELAXED, SC_SYS);
}

__device__ __forceinline__ int tags_ok4(const unsigned long long* u, unsigned long long tpat) {
  unsigned long long m = 0;
  #pragma unroll
  for (int j = 0; j < 4; ++j) m |= (u[j] & 0xFFFF0000FFFF0000ull) ^ tpat;
  return m == 0;
}

__device__ __forceinline__ short8b unpack_frag(const unsigned long long* u) {
  union { unsigned d[4]; short8b v; } r;
  #pragma unroll
  for (int j = 0; j < 4; ++j)
    r.d[j] = (unsigned)(u[j] & 0xFFFFu) | (unsigned)((u[j] >> 16) & 0xFFFF0000u);
  return r.v;
}

// Persistent LSTM kernel, PLAIN launch (256 blocks x 128 thr; 64KiB LDS each =>
// exactly 1 block/CU, all co-resident => spin-wait progress is guaranteed).
// Forward sync: per-dword epoch tags on h. Backward throttle: cnt[t] arrivals.
__global__ __launch_bounds__(NTHR, 1)
void lstm_kernel(const unsigned short* __restrict__ xb,
                 const float* __restrict__ Wf, const float* __restrict__ Wi,
                 const float* __restrict__ Wo, const float* __restrict__ Wc,
                 const float* __restrict__ bfp, const float* __restrict__ bip,
                 const float* __restrict__ bop, const float* __restrict__ bcp,
                 float* __restrict__ out, unsigned* __restrict__ hbufd,
                 int* __restrict__ cnt)
{
  __shared__ unsigned short Wl[16 * 2048];  // 64 KiB weight stripe (bf16, swizzled)
  const int tid = threadIdx.x;
  const int bid = blockIdx.x;
  const int j0  = bid * 4;

  {
    const float* Wg[4] = {Wf, Wi, Wo, Wc};
    for (int g = 0; g < 4; ++g) {
      const float* Wp = Wg[g] + j0;
      for (int k = tid; k < K_; k += NTHR) {
        float4 w = *reinterpret_cast<const float4*>(Wp + (long)k * H_);
        float wv[4] = {w.x, w.y, w.z, w.w};
        #pragma unroll
        for (int cj = 0; cj < 4; ++cj) {
          int n = g * 4 + cj;
          int byteoff = n * 4096 + ((2 * k) ^ ((n & 7) << 4));
          *reinterpret_cast<unsigned short*>(reinterpret_cast<char*>(Wl) + byteoff) = f2bf(wv[cj]);
        }
      }
    }
  }
  __syncthreads();

  const int lane = tid & 63;
  const int m    = tid >> 6;
  const int lr   = lane & 15;
  const int lg   = lane >> 4;
  const int b    = m * 16 + lr;     // batch row fed into A-fragment
  const int cj   = lane & 3;        // H-column (within block) this lane gates
  const int gb0  = m * 16 + lg * 4; // first batch row this lane gates

  const float bias_f = bfp[j0 + cj];
  const float bias_i = bip[j0 + cj];
  const float bias_o = bop[j0 + cj];
  const float bias_g = bcp[j0 + cj];

  float creg[4] = {0.f, 0.f, 0.f, 0.f};  // c state in registers for all T steps

  const char* WlB   = reinterpret_cast<const char*>(Wl);
  const int colbase = lr * 4096;
  const int swz     = (lr & 7) << 4;

  // x-part GEMM for step t (off critical path)
  auto xpart = [&](int t, f32x4& a0, f32x4& a1) {
    a0 = f32x4{0.f, 0.f, 0.f, 0.f};
    a1 = f32x4{0.f, 0.f, 0.f, 0.f};
    const unsigned short* aptr = xb + (((long)(t * B_ + b)) << 10) + lg * 8;
    #pragma unroll
    for (int it = 0; it < 32; ++it) {
      short8b a  = *reinterpret_cast<const short8b*>(aptr + it * 32);
      short8b bb = *reinterpret_cast<const short8b*>(WlB + colbase + ((it * 64 + lg * 16) ^ swz));
      if (it & 1) a1 = __builtin_amdgcn_mfma_f32_16x16x32_bf16(a, bb, a1, 0, 0, 0);
      else        a0 = __builtin_amdgcn_mfma_f32_16x16x32_bf16(a, bb, a0, 0, 0, 0);
    }
  };

  f32x4 xa0, xa1;
  xpart(0, xa0, xa1);

  for (int t = 0; t < T_; ++t) {
    // ---- h-part GEMM with tag-polled reads (expected epoch = t) ----
    // h[t-1] lives in hbufd[t&1] (buf0 = even epochs); memset zeros = epoch-0 h0.
    const unsigned* base = hbufd + (t & 1) * BH + (b << 10) + lg * 8;
    const unsigned long long tpat =
        ((unsigned long long)t << 48) | ((unsigned long long)t << 16);

    f32x4 a0 = xa0, a1 = xa1;

    unsigned long long u0[8][4], u1[8][4];

    auto issue_group = [&](int g, unsigned long long (&u)[8][4]) {
      #pragma unroll
      for (int f = 0; f < 8; ++f) ld_frag8(base + (g * 8 + f) * 32, u[f]);
    };
    auto verify_group = [&](int g, unsigned long long (&u)[8][4]) {
      while (true) {
        int ok = 1;
        #pragma unroll
        for (int f = 0; f < 8; ++f) ok &= tags_ok4(u[f], tpat);
        if (__all(ok)) break;                 // wave-uniform retry
        __builtin_amdgcn_s_sleep(1);
        #pragma unroll
        for (int f = 0; f < 8; ++f) ld_frag8(base + (g * 8 + f) * 32, u[f]);
      }
    };

    issue_group(0, u0);
    #pragma unroll
    for (int g = 0; g < 4; ++g) {            // static u0/u1 alternation
      unsigned long long (&uc)[8][4] = (g & 1) ? u1 : u0;
      unsigned long long (&un)[8][4] = (g & 1) ? u0 : u1;
      if (g < 3) issue_group(g + 1, un);     // next group in flight during MFMAs
      verify_group(g, uc);
      #pragma unroll
      for (int f = 0; f < 8; ++f) {
        const int it = g * 8 + f;
        short8b a  = unpack_frag(uc[f]);
        short8b bb = *reinterpret_cast<const short8b*>(
            WlB + colbase + ((2048 + it * 64 + lg * 16) ^ swz));
        if (it & 1) a1 = __builtin_amdgcn_mfma_f32_16x16x32_bf16(a, bb, a1, 0, 0, 0);
        else        a0 = __builtin_amdgcn_mfma_f32_16x16x32_bf16(a, bb, a0, 0, 0, 0);
      }
    }
    f32x4 acc = a0 + a1;

    // ---- gates: D[row=lg*4+r][col=lr]; lane wants cols g*4+cj ----
    float gate[4][4];
    #pragma unroll
    for (int g = 0; g < 4; ++g) {
      const int src = lg * 16 + g * 4 + cj;
      #pragma unroll
      for (int r = 0; r < 4; ++r) gate[g][r] = __shfl(acc[r], src, 64);
    }

    float hv[4];
    #pragma unroll
    for (int r = 0; r < 4; ++r) {
      float fg = sig_(gate[0][r] + bias_f);
      float ig = sig_(gate[1][r] + bias_i);
      float og = sig_(gate[2][r] + bias_o);
      float gg = tanh_(gate[3][r] + bias_g);
      float c  = fg * creg[r] + ig * gg;
      creg[r]  = c;
      hv[r]    = og * tanh_(c);
    }

    if (t < T_ - 1) {
      // ---- throttle: buf[(t+1)&1] was read by all blocks at step t-1? ----
      if (t > 0) {
        if (tid == 0) {
          while (__hip_atomic_load(&cnt[t - 1], __ATOMIC_RELAXED, SC_SYS) < NB)
            __builtin_amdgcn_s_sleep(1);
        }
        __syncthreads();
      }
      // ---- publish h[t] with epoch tag t+1 (system-scope stores) ----
      unsigned* hn = hbufd + ((t + 1) & 1) * BH;
      if ((lane & 12) == 0) {
        #pragma unroll
        for (int r = 0; r < 4; ++r) {
          unsigned v = (unsigned)f2bf(hv[r]) | ((unsigned)(t + 1) << 16);
          __hip_atomic_store(&hn[(gb0 + r) * H_ + j0 + cj], v, __ATOMIC_RELAXED, SC_SYS);
        }
      }
    }

    // ---- arrive: this block's reads of buf[t&1] are complete ----
    __syncthreads();
    if (t < T_ - 1 && tid == 0)
      __hip_atomic_fetch_add(&cnt[t], 1, __ATOMIC_RELAXED, SC_SYS);

    // ---- out stores + next x-part (off critical path) ----
    if ((lane & 12) == 0) {
      #pragma unroll
      for (int r = 0; r < 4; ++r) {
        const int row  = gb0 + r;
        const int colj = j0 + cj;
        const long oh  = (long)(t * B_ + row) * H_ + colj;
        out[HLAST + oh]       = hv[r];
        out[HLAST + TBH + oh] = creg[r];
        if (t == T_ - 1) out[(long)row * H_ + colj] = hv[r];
      }
    }

    if (t + 1 < T_) xpart(t + 1, xa0, xa1);
  }
}

// Fallback (ws too small): per-step kernel gathering raw f32 each step.
__global__ void lstm_step_fallback_kernel(int t,
    const float* __restrict__ xf,
    const float* __restrict__ Wf, const float* __restrict__ Wi,
    const float* __restrict__ Wo, const float* __restrict__ Wc,
    const float* __restrict__ bfp, const float* __restrict__ bip,
    const float* __restrict__ bop, const float* __restrict__ bcp,
    float* __restrict__ out, unsigned short* __restrict__ hbuf)
{
  const int tid  = threadIdx.x;
  const int bid  = blockIdx.x;
  const int lane = tid & 63;
  const int m    = tid >> 6;
  const int lr   = lane & 15;
  const int lg   = lane >> 4;
  const int b    = m * 16 + lr;
  const int cj   = lane & 3;
  const int j0   = bid * 4;
  const int gb0  = m * 16 + lg * 4;

  const unsigned short* hcur = hbuf + (t & 1) * BH;
  f32x4 a0 = {0.f, 0.f, 0.f, 0.f};
  f32x4 a1 = {0.f, 0.f, 0.f, 0.f};

  const int g    = lr >> 2;
  const int colg = j0 + (lr & 3);
  const float* Wg = (g == 0) ? Wf : (g == 1) ? Wi : (g == 2) ? Wo : Wc;
  const float* axf = xf + ((long)b * T_ + t) * I_ + lg * 8;
  const unsigned short* ah = hcur + (b << 10) + lg * 8;
  #pragma unroll 4
  for (int it = 0; it < 32; ++it) {
    const int k0 = it * 32 + lg * 8;
    short8b a, bb;
    #pragma unroll
    for (int e = 0; e < 8; ++e) {
      a[e]  = (short)f2bf(axf[it * 32 + e]);
      bb[e] = (short)f2bf(Wg[(size_t)(k0 + e) * H_ + colg]);
    }
    if (it & 1) a1 = __builtin_amdgcn_mfma_f32_16x16x32_bf16(a, bb, a1, 0, 0, 0);
    else        a0 = __builtin_amdgcn_mfma_f32_16x16x32_bf16(a, bb, a0, 0, 0, 0);
  }
  #pragma unroll 4
  for (int it = 0; it < 32; ++it) {
    const int k0 = 1024 + it * 32 + lg * 8;
    short8b a = *reinterpret_cast<const short8b*>(ah + it * 32);
    short8b bb;
    #pragma unroll
    for (int e = 0; e < 8; ++e)
      bb[e] = (short)f2bf(Wg[(size_t)(k0 + e) * H_ + colg]);
    if (it & 1) a1 = __builtin_amdgcn_mfma_f32_16x16x32_bf16(a, bb, a1, 0, 0, 0);
    else        a0 = __builtin_amdgcn_mfma_f32_16x16x32_bf16(a, bb, a0, 0, 0, 0);
  }
  f32x4 acc = a0 + a1;

  float gate[4][4];
  #pragma unroll
  for (int gg = 0; gg < 4; ++gg) {
    const int src = lg * 16 + gg * 4 + cj;
    #pragma unroll
    for (int r = 0; r < 4; ++r) gate[gg][r] = __shfl(acc[r], src, 64);
  }

  if ((lane & 12) == 0) {
    const int col = j0 + cj;
    const float bias_f = bfp[col];
    const float bias_i = bip[col];
    const float bias_o = bop[col];
    const float bias_g = bcp[col];
    #pragma unroll
    for (int r = 0; r < 4; ++r) {
      const int row = gb0 + r;
      float cp = (t == 0) ? 0.f
               : out[HLAST + TBH + (long)((t - 1) * B_ + row) * H_ + col];
      float fg = sig_(gate[0][r] + bias_f);
      float ig = sig_(gate[1][r] + bias_i);
      float og = sig_(gate[2][r] + bias_o);
      float gv = tanh_(gate[3][r] + bias_g);
      float c  = fg * cp + ig * gv;
      float hv = og * tanh_(c);
      const long oh = (long)(t * B_ + row) * H_ + col;
      out[HLAST + oh]       = hv;
      out[HLAST + TBH + oh] = c;
      hbuf[((t + 1) & 1) * BH + row * H_ + col] = f2bf(hv);
      if (t == T_ - 1) out[(long)row * H_ + col] = hv;
    }
  }
}

extern "C" void kernel_launch(void* const* d_in, const int* in_sizes, int n_in,
                              void* d_out, int out_size, void* d_ws, size_t ws_size,
                              hipStream_t stream) {
  const float* x   = (const float*)d_in[0];
  const float* Wf  = (const float*)d_in[1];
  const float* bf_ = (const float*)d_in[2];
  const float* Wi  = (const float*)d_in[3];
  const float* bi_ = (const float*)d_in[4];
  const float* Wo  = (const float*)d_in[5];
  const float* bo_ = (const float*)d_in[6];
  const float* Wc  = (const float*)d_in[7];
  const float* bc_ = (const float*)d_in[8];
  float* out = (float*)d_out;

  const size_t xb_bytes   = (size_t)T_ * B_ * I_ * 2;     // 32 MiB
  const size_t hbuf_bytes = (size_t)2 * BH * 4;           // 256 KiB (tagged dwords)
  const size_t cnt_bytes  = (size_t)T_ * sizeof(int);     // 2 KiB
  const bool fast = ws_size >= xb_bytes + hbuf_bytes + cnt_bytes;

  if (fast) {
    unsigned short* xb = (unsigned short*)d_ws;
    unsigned* hbufd    = (unsigned*)((char*)d_ws + xb_bytes);
    int* cnt           = (int*)((char*)d_ws + xb_bytes + hbuf_bytes);

    // zero tagged h buffers (tag 0 == epoch of h0, value 0) + counters — every call
    (void)hipMemsetAsync(hbufd, 0, hbuf_bytes + cnt_bytes, stream);

    const int total_vec = T_ * B_ * I_ / 4;
    convert_x_kernel<<<dim3(total_vec / 256), dim3(256), 0, stream>>>(x, xb);

    lstm_kernel<<<dim3(NB), dim3(NTHR), 0, stream>>>(
        xb, Wf, Wi, Wo, Wc, bf_, bi_, bo_, bc_, out, hbufd, cnt);
  } else {
    unsigned short* hbuf = (unsigned short*)d_ws;
    (void)hipMemsetAsync(hbuf, 0, (size_t)2 * BH * 2, stream);
    for (int t = 0; t < T_; ++t)
      lstm_step_fallback_kernel<<<dim3(NB), dim3(NTHR), 0, stream>>>(
          t, x, Wf, Wi, Wo, Wc, bf_, bi_, bo_, bc_, out, hbuf);
  }
}

// Round 7
// 4238.199 us; speedup vs baseline: 1.5091x; 1.5091x over previous
//
#include <hip/hip_runtime.h>

typedef __attribute__((ext_vector_type(8))) short short8b;
typedef __attribute__((ext_vector_type(4))) float f32x4;

#define B_   32
#define T_   512
#define I_   1024
#define H_   1024
#define K_   2048          // I + H
#define NB   256           // blocks, each owns 4 H-cols (16 gate cols); 1 per CU
#define NTHR 128           // 2 waves: wave m handles batch rows m*16..m*16+15
#define BH   (B_ * H_)
#define HLAST (B_ * H_)
#define TBH ((long)T_ * B_ * H_)
#define SC_SYS __HIP_MEMORY_SCOPE_SYSTEM

__device__ __forceinline__ unsigned short f2bf(float f) {
  union { float f; unsigned u; } c; c.f = f;
  unsigned r = (c.u + 0x7FFFu + ((c.u >> 16) & 1u)) >> 16;  // RNE
  return (unsigned short)r;
}

__device__ __forceinline__ float sig_(float x)  { return 1.0f / (1.0f + __expf(-x)); }
__device__ __forceinline__ float tanh_(float x) { return 1.0f - 2.0f / (__expf(2.0f * x) + 1.0f); }

__device__ __forceinline__ unsigned long long ld64sys(const void* p) {
  return __hip_atomic_load((const unsigned long long*)p, __ATOMIC_RELAXED, SC_SYS);
}

// x [B][T][I] f32  ->  xb [T][B][I] bf16 (step-t slab contiguous)
__global__ void convert_x_kernel(const float* __restrict__ x, unsigned short* __restrict__ xb) {
  long vid = (long)blockIdx.x * blockDim.x + threadIdx.x;
  long o = vid * 4;
  if (o >= (long)T_ * B_ * I_) return;
  int i  = (int)(o & (I_ - 1));
  long bt = o >> 10;
  int b  = (int)(bt & (B_ - 1));
  int t  = (int)(bt >> 5);
  float4 v = *reinterpret_cast<const float4*>(x + (((long)b * T_ + t) << 10) + i);
  ushort4 pk;
  pk.x = f2bf(v.x); pk.y = f2bf(v.y); pk.z = f2bf(v.z); pk.w = f2bf(v.w);
  *reinterpret_cast<ushort4*>(xb + o) = pk;
}

// Persistent LSTM, plain launch (256 blocks x 128 thr, 64 KiB LDS -> 1 block/CU,
// all co-resident). h history is WRITE-ONCE per step (no reuse -> no throttle).
// Forward sync: system stores -> vmcnt(0) -> cnt[t] add; readers poll cnt once.
// HB16: h read from bf16 hseq slab in ws. Else: h read f32 from h_states output.
template <bool HB16>
__global__ __launch_bounds__(NTHR, 1)
void lstm_kernel(const unsigned short* __restrict__ xb,
                 const float* __restrict__ Wf, const float* __restrict__ Wi,
                 const float* __restrict__ Wo, const float* __restrict__ Wc,
                 const float* __restrict__ bfp, const float* __restrict__ bip,
                 const float* __restrict__ bop, const float* __restrict__ bcp,
                 float* __restrict__ out, unsigned short* __restrict__ hseq,
                 int* __restrict__ cnt)
{
  __shared__ unsigned short Wl[16 * 2048];  // 64 KiB weight stripe (bf16, swizzled)
  const int tid = threadIdx.x;
  const int bid = blockIdx.x;
  const int j0  = bid * 4;

  {
    const float* Wg[4] = {Wf, Wi, Wo, Wc};
    for (int g = 0; g < 4; ++g) {
      const float* Wp = Wg[g] + j0;
      for (int k = tid; k < K_; k += NTHR) {
        float4 w = *reinterpret_cast<const float4*>(Wp + (long)k * H_);
        float wv[4] = {w.x, w.y, w.z, w.w};
        #pragma unroll
        for (int cj = 0; cj < 4; ++cj) {
          int n = g * 4 + cj;
          int byteoff = n * 4096 + ((2 * k) ^ ((n & 7) << 4));
          *reinterpret_cast<unsigned short*>(reinterpret_cast<char*>(Wl) + byteoff) = f2bf(wv[cj]);
        }
      }
    }
  }
  __syncthreads();

  const int lane = tid & 63;
  const int m    = tid >> 6;
  const int lr   = lane & 15;
  const int lg   = lane >> 4;
  const int b    = m * 16 + lr;     // batch row fed into A-fragment
  const int cj   = lane & 3;        // H-column (within block) this lane gates
  const int gb0  = m * 16 + lg * 4; // first batch row this lane gates

  const float bias_f = bfp[j0 + cj];
  const float bias_i = bip[j0 + cj];
  const float bias_o = bop[j0 + cj];
  const float bias_g = bcp[j0 + cj];

  float creg[4] = {0.f, 0.f, 0.f, 0.f};  // c state in registers for all T steps

  const char* WlB   = reinterpret_cast<const char*>(Wl);
  const int colbase = lr * 4096;
  const int swz     = (lr & 7) << 4;

  // x-part GEMM for step t (off critical path)
  auto xpart = [&](int t, f32x4& a0, f32x4& a1) {
    a0 = f32x4{0.f, 0.f, 0.f, 0.f};
    a1 = f32x4{0.f, 0.f, 0.f, 0.f};
    const unsigned short* aptr = xb + (((long)(t * B_ + b)) << 10) + lg * 8;
    #pragma unroll
    for (int it = 0; it < 32; ++it) {
      short8b a  = *reinterpret_cast<const short8b*>(aptr + it * 32);
      short8b bb = *reinterpret_cast<const short8b*>(WlB + colbase + ((it * 64 + lg * 16) ^ swz));
      if (it & 1) a1 = __builtin_amdgcn_mfma_f32_16x16x32_bf16(a, bb, a1, 0, 0, 0);
      else        a0 = __builtin_amdgcn_mfma_f32_16x16x32_bf16(a, bb, a0, 0, 0, 0);
    }
  };

  f32x4 xa0, xa1;
  xpart(0, xa0, xa1);

  for (int t = 0; t < T_; ++t) {
    f32x4 a0 = xa0, a1 = xa1;

    if (t > 0) {
      // ---- one rendezvous: wait until all blocks published h[t-1] ----
      while (__hip_atomic_load(&cnt[t - 1], __ATOMIC_RELAXED, SC_SYS) < NB)
        __builtin_amdgcn_s_sleep(1);

      if (HB16) {
        const unsigned short* base = hseq + (long)(t - 1) * BH + (b << 10) + lg * 8;
        unsigned long long u0[8][2], u1[8][2];
        auto issue = [&](int g, unsigned long long (&u)[8][2]) {
          #pragma unroll
          for (int f = 0; f < 8; ++f) {
            u[f][0] = ld64sys(base + (g * 8 + f) * 32);
            u[f][1] = ld64sys(base + (g * 8 + f) * 32 + 4);
          }
        };
        issue(0, u0);
        #pragma unroll
        for (int g = 0; g < 4; ++g) {
          unsigned long long (&uc)[8][2] = (g & 1) ? u1 : u0;
          unsigned long long (&un)[8][2] = (g & 1) ? u0 : u1;
          if (g < 3) issue(g + 1, un);
          #pragma unroll
          for (int f = 0; f < 8; ++f) {
            const int it = g * 8 + f;
            union { unsigned long long q[2]; short8b v; } cv;
            cv.q[0] = uc[f][0]; cv.q[1] = uc[f][1];
            short8b bb = *reinterpret_cast<const short8b*>(
                WlB + colbase + ((2048 + it * 64 + lg * 16) ^ swz));
            if (it & 1) a1 = __builtin_amdgcn_mfma_f32_16x16x32_bf16(cv.v, bb, a1, 0, 0, 0);
            else        a0 = __builtin_amdgcn_mfma_f32_16x16x32_bf16(cv.v, bb, a0, 0, 0, 0);
          }
        }
      } else {
        const float* basef = out + HLAST + ((long)(t - 1) * B_ + b) * H_ + lg * 8;
        unsigned long long u0[8][4], u1[8][4];
        auto issue = [&](int g, unsigned long long (&u)[8][4]) {
          #pragma unroll
          for (int f = 0; f < 8; ++f)
            #pragma unroll
            for (int j = 0; j < 4; ++j)
              u[f][j] = ld64sys(basef + (g * 8 + f) * 32 + j * 2);
        };
        issue(0, u0);
        #pragma unroll
        for (int g = 0; g < 4; ++g) {
          unsigned long long (&uc)[8][4] = (g & 1) ? u1 : u0;
          unsigned long long (&un)[8][4] = (g & 1) ? u0 : u1;
          if (g < 3) issue(g + 1, un);
          #pragma unroll
          for (int f = 0; f < 8; ++f) {
            const int it = g * 8 + f;
            short8b a;
            #pragma unroll
            for (int j = 0; j < 4; ++j) {
              a[2 * j]     = (short)f2bf(__uint_as_float((unsigned)(uc[f][j] & 0xFFFFFFFFu)));
              a[2 * j + 1] = (short)f2bf(__uint_as_float((unsigned)(uc[f][j] >> 32)));
            }
            short8b bb = *reinterpret_cast<const short8b*>(
                WlB + colbase + ((2048 + it * 64 + lg * 16) ^ swz));
            if (it & 1) a1 = __builtin_amdgcn_mfma_f32_16x16x32_bf16(a, bb, a1, 0, 0, 0);
            else        a0 = __builtin_amdgcn_mfma_f32_16x16x32_bf16(a, bb, a0, 0, 0, 0);
          }
        }
      }
    }

    f32x4 acc = a0 + a1;

    // ---- gates: D[row=lg*4+r][col=lr]; lane wants cols g*4+cj ----
    float gate[4][4];
    #pragma unroll
    for (int g = 0; g < 4; ++g) {
      const int src = lg * 16 + g * 4 + cj;
      #pragma unroll
      for (int r = 0; r < 4; ++r) gate[g][r] = __shfl(acc[r], src, 64);
    }

    float hv[4];
    #pragma unroll
    for (int r = 0; r < 4; ++r) {
      float fg = sig_(gate[0][r] + bias_f);
      float ig = sig_(gate[1][r] + bias_i);
      float og = sig_(gate[2][r] + bias_o);
      float gg = tanh_(gate[3][r] + bias_g);
      float c  = fg * creg[r] + ig * gg;
      creg[r]  = c;
      hv[r]    = og * tanh_(c);
    }

    // ---- publish h[t] (system stores), then ack -> arrive ----
    if (t < T_ - 1) {
      if (HB16) {
        unsigned hw[4];
        #pragma unroll
        for (int r = 0; r < 4; ++r) {
          unsigned mine  = f2bf(hv[r]);
          unsigned other = (unsigned)__shfl((int)mine, lane ^ 1, 64);
          hw[r] = mine | (other << 16);            // valid on even-cj writer lanes
        }
        if ((lane & 12) == 0 && (cj & 1) == 0) {
          unsigned short* hp = hseq + (long)t * BH;
          #pragma unroll
          for (int r = 0; r < 4; ++r)
            __hip_atomic_store((unsigned*)(hp + (gb0 + r) * H_ + j0 + cj), hw[r],
                               __ATOMIC_RELAXED, SC_SYS);
        }
      } else {
        if ((lane & 12) == 0) {
          #pragma unroll
          for (int r = 0; r < 4; ++r)
            __hip_atomic_store((unsigned*)&out[HLAST + (long)(t * B_ + gb0 + r) * H_ + j0 + cj],
                               __float_as_uint(hv[r]), __ATOMIC_RELAXED, SC_SYS);
        }
      }
      asm volatile("s_waitcnt vmcnt(0)" ::: "memory");   // stores acked at MALL
      __syncthreads();                                    // both waves' stores acked
      if (tid == 0)
        __hip_atomic_fetch_add(&cnt[t], 1, __ATOMIC_RELAXED, SC_SYS);
    }

    // ---- plain out stores + next x-part (off critical path) ----
    if ((lane & 12) == 0) {
      #pragma unroll
      for (int r = 0; r < 4; ++r) {
        const int row  = gb0 + r;
        const int colj = j0 + cj;
        const long oh  = (long)(t * B_ + row) * H_ + colj;
        if (HB16 || t == T_ - 1) out[HLAST + oh] = hv[r];  // f32 path stored it above
        out[HLAST + TBH + oh] = creg[r];
        if (t == T_ - 1) out[(long)row * H_ + colj] = hv[r];
      }
    }

    if (t + 1 < T_) xpart(t + 1, xa0, xa1);
  }
}

// Fallback (ws too small): per-step kernel gathering raw f32 each step.
__global__ void lstm_step_fallback_kernel(int t,
    const float* __restrict__ xf,
    const float* __restrict__ Wf, const float* __restrict__ Wi,
    const float* __restrict__ Wo, const float* __restrict__ Wc,
    const float* __restrict__ bfp, const float* __restrict__ bip,
    const float* __restrict__ bop, const float* __restrict__ bcp,
    float* __restrict__ out, unsigned short* __restrict__ hbuf)
{
  const int tid  = threadIdx.x;
  const int bid  = blockIdx.x;
  const int lane = tid & 63;
  const int m    = tid >> 6;
  const int lr   = lane & 15;
  const int lg   = lane >> 4;
  const int b    = m * 16 + lr;
  const int cj   = lane & 3;
  const int j0   = bid * 4;
  const int gb0  = m * 16 + lg * 4;

  const unsigned short* hcur = hbuf + (t & 1) * BH;
  f32x4 a0 = {0.f, 0.f, 0.f, 0.f};
  f32x4 a1 = {0.f, 0.f, 0.f, 0.f};

  const int g    = lr >> 2;
  const int colg = j0 + (lr & 3);
  const float* Wg = (g == 0) ? Wf : (g == 1) ? Wi : (g == 2) ? Wo : Wc;
  const float* axf = xf + ((long)b * T_ + t) * I_ + lg * 8;
  const unsigned short* ah = hcur + (b << 10) + lg * 8;
  #pragma unroll 4
  for (int it = 0; it < 32; ++it) {
    const int k0 = it * 32 + lg * 8;
    short8b a, bb;
    #pragma unroll
    for (int e = 0; e < 8; ++e) {
      a[e]  = (short)f2bf(axf[it * 32 + e]);
      bb[e] = (short)f2bf(Wg[(size_t)(k0 + e) * H_ + colg]);
    }
    if (it & 1) a1 = __builtin_amdgcn_mfma_f32_16x16x32_bf16(a, bb, a1, 0, 0, 0);
    else        a0 = __builtin_amdgcn_mfma_f32_16x16x32_bf16(a, bb, a0, 0, 0, 0);
  }
  #pragma unroll 4
  for (int it = 0; it < 32; ++it) {
    const int k0 = 1024 + it * 32 + lg * 8;
    short8b a = *reinterpret_cast<const short8b*>(ah + it * 32);
    short8b bb;
    #pragma unroll
    for (int e = 0; e < 8; ++e)
      bb[e] = (short)f2bf(Wg[(size_t)(k0 + e) * H_ + colg]);
    if (it & 1) a1 = __builtin_amdgcn_mfma_f32_16x16x32_bf16(a, bb, a1, 0, 0, 0);
    else        a0 = __builtin_amdgcn_mfma_f32_16x16x32_bf16(a, bb, a0, 0, 0, 0);
  }
  f32x4 acc = a0 + a1;

  float gate[4][4];
  #pragma unroll
  for (int gg = 0; gg < 4; ++gg) {
    const int src = lg * 16 + gg * 4 + cj;
    #pragma unroll
    for (int r = 0; r < 4; ++r) gate[gg][r] = __shfl(acc[r], src, 64);
  }

  if ((lane & 12) == 0) {
    const int col = j0 + cj;
    const float bias_f = bfp[col];
    const float bias_i = bip[col];
    const float bias_o = bop[col];
    const float bias_g = bcp[col];
    #pragma unroll
    for (int r = 0; r < 4; ++r) {
      const int row = gb0 + r;
      float cp = (t == 0) ? 0.f
               : out[HLAST + TBH + (long)((t - 1) * B_ + row) * H_ + col];
      float fg = sig_(gate[0][r] + bias_f);
      float ig = sig_(gate[1][r] + bias_i);
      float og = sig_(gate[2][r] + bias_o);
      float gv = tanh_(gate[3][r] + bias_g);
      float c  = fg * cp + ig * gv;
      float hv = og * tanh_(c);
      const long oh = (long)(t * B_ + row) * H_ + col;
      out[HLAST + oh]       = hv;
      out[HLAST + TBH + oh] = c;
      hbuf[((t + 1) & 1) * BH + row * H_ + col] = f2bf(hv);
      if (t == T_ - 1) out[(long)row * H_ + col] = hv;
    }
  }
}

extern "C" void kernel_launch(void* const* d_in, const int* in_sizes, int n_in,
                              void* d_out, int out_size, void* d_ws, size_t ws_size,
                              hipStream_t stream) {
  const float* x   = (const float*)d_in[0];
  const float* Wf  = (const float*)d_in[1];
  const float* bf_ = (const float*)d_in[2];
  const float* Wi  = (const float*)d_in[3];
  const float* bi_ = (const float*)d_in[4];
  const float* Wo  = (const float*)d_in[5];
  const float* bo_ = (const float*)d_in[6];
  const float* Wc  = (const float*)d_in[7];
  const float* bc_ = (const float*)d_in[8];
  float* out = (float*)d_out;

  const size_t xb_bytes   = (size_t)T_ * B_ * I_ * 2;       // 32 MiB
  const size_t hseq_bytes = (size_t)T_ * BH * 2;            // 32 MiB (bf16 h history)
  const size_t cnt_bytes  = (size_t)T_ * sizeof(int);       // 2 KiB

  const bool has_xb   = ws_size >= xb_bytes + cnt_bytes;
  const bool has_hseq = ws_size >= xb_bytes + hseq_bytes + cnt_bytes;

  if (has_xb) {
    unsigned short* xb   = (unsigned short*)d_ws;
    unsigned short* hseq = has_hseq ? (unsigned short*)((char*)d_ws + xb_bytes) : xb;
    int* cnt = (int*)((char*)d_ws + (has_hseq ? xb_bytes + hseq_bytes : xb_bytes));

    (void)hipMemsetAsync(cnt, 0, cnt_bytes, stream);   // every call (graph replay safe)

    const int total_vec = T_ * B_ * I_ / 4;
    convert_x_kernel<<<dim3(total_vec / 256), dim3(256), 0, stream>>>(x, xb);

    if (has_hseq)
      lstm_kernel<true><<<dim3(NB), dim3(NTHR), 0, stream>>>(
          xb, Wf, Wi, Wo, Wc, bf_, bi_, bo_, bc_, out, hseq, cnt);
    else
      lstm_kernel<false><<<dim3(NB), dim3(NTHR), 0, stream>>>(
          xb, Wf, Wi, Wo, Wc, bf_, bi_, bo_, bc_, out, hseq, cnt);
  } else {
    unsigned short* hbuf = (unsigned short*)d_ws;
    (void)hipMemsetAsync(hbuf, 0, (size_t)2 * BH * 2, stream);
    for (int t = 0; t < T_; ++t)
      lstm_step_fallback_kernel<<<dim3(NB), dim3(NTHR), 0, stream>>>(
          t, x, Wf, Wi, Wo, Wc, bf_, bi_, bo_, bc_, out, hbuf);
  }
}

// Round 8
// 4079.848 us; speedup vs baseline: 1.5677x; 1.0388x over previous
//
#include <hip/hip_runtime.h>
#include <hip/hip_bf16.h>

typedef __attribute__((ext_vector_type(8))) short short8b;
typedef __attribute__((ext_vector_type(4))) float f32x4;

#define B_   32
#define T_   512
#define I_   1024
#define H_   1024
#define K_   2048          // I + H
#define NB   256           // blocks, each owns 4 H-cols (16 gate cols); 1 per CU
#define NTHR 128           // 2 waves: wave m handles batch rows m*16..m*16+15
#define BH   (B_ * H_)
#define HLAST (B_ * H_)
#define TBH ((long)T_ * B_ * H_)
#define SC_SYS __HIP_MEMORY_SCOPE_SYSTEM
#define MAGIC 0x5AB00000u   // flag value = MAGIC|t; != 0 (memset) and != 0xAAAAAAAA (poison)

__device__ __forceinline__ unsigned short f2bf(float f) {
  union { float f; unsigned u; } c; c.f = f;
  unsigned r = (c.u + 0x7FFFu + ((c.u >> 16) & 1u)) >> 16;  // RNE
  return (unsigned short)r;
}

__device__ __forceinline__ float sig_(float x)  { return 1.0f / (1.0f + __expf(-x)); }
__device__ __forceinline__ float tanh_(float x) { return 1.0f - 2.0f / (__expf(2.0f * x) + 1.0f); }

__device__ __forceinline__ unsigned long long ld64sys(const void* p) {
  return __hip_atomic_load((const unsigned long long*)p, __ATOMIC_RELAXED, SC_SYS);
}

// x [B][T][I] f32  ->  xb [T][B][I] bf16 (step-t slab contiguous)
__global__ void convert_x_kernel(const float* __restrict__ x, unsigned short* __restrict__ xb) {
  long vid = (long)blockIdx.x * blockDim.x + threadIdx.x;
  long o = vid * 4;
  if (o >= (long)T_ * B_ * I_) return;
  int i  = (int)(o & (I_ - 1));
  long bt = o >> 10;
  int b  = (int)(bt & (B_ - 1));
  int t  = (int)(bt >> 5);
  float4 v = *reinterpret_cast<const float4*>(x + (((long)b * T_ + t) << 10) + i);
  ushort4 pk;
  pk.x = f2bf(v.x); pk.y = f2bf(v.y); pk.z = f2bf(v.z); pk.w = f2bf(v.w);
  *reinterpret_cast<ushort4*>(xb + o) = pk;
}

// Persistent LSTM, plain launch. Publish = the f32 h_states output store itself
// (system-scope, write-through to MALL) + per-WAVE flag after vmcnt(0) ack.
// Consume = poll 512 flags (system loads), then PLAIN CACHED f32 h reads:
// legal because h addresses are write-once & read-only-after-flag, and the
// one-time agent-acquire fence below purges any pre-kernel L1/L2 residue.
__global__ __launch_bounds__(NTHR, 1)
void lstm_kernel(const unsigned short* __restrict__ xb,
                 const float* __restrict__ Wf, const float* __restrict__ Wi,
                 const float* __restrict__ Wo, const float* __restrict__ Wc,
                 const float* __restrict__ bfp, const float* __restrict__ bip,
                 const float* __restrict__ bop, const float* __restrict__ bcp,
                 float* __restrict__ out, unsigned* __restrict__ flags)
{
  __shared__ unsigned short Wl[16 * 2048];  // 64 KiB weight stripe (bf16, swizzled)
  const int tid = threadIdx.x;
  const int bid = blockIdx.x;
  const int j0  = bid * 4;

  {
    const float* Wg[4] = {Wf, Wi, Wo, Wc};
    for (int g = 0; g < 4; ++g) {
      const float* Wp = Wg[g] + j0;
      for (int k = tid; k < K_; k += NTHR) {
        float4 w = *reinterpret_cast<const float4*>(Wp + (long)k * H_);
        float wv[4] = {w.x, w.y, w.z, w.w};
        #pragma unroll
        for (int cj = 0; cj < 4; ++cj) {
          int n = g * 4 + cj;
          int byteoff = n * 4096 + ((2 * k) ^ ((n & 7) << 4));
          *reinterpret_cast<unsigned short*>(reinterpret_cast<char*>(Wl) + byteoff) = f2bf(wv[cj]);
        }
      }
    }
  }
  __syncthreads();

  // One-time purge of pre-kernel cache residue (harness poison/memset of out).
  // After this, every h_states line filled into L1/L2 is fresh-by-construction.
  __builtin_amdgcn_fence(__ATOMIC_ACQUIRE, "agent");

  const int lane = tid & 63;
  const int m    = tid >> 6;
  const int lr   = lane & 15;
  const int lg   = lane >> 4;
  const int b    = m * 16 + lr;     // batch row fed into A-fragment
  const int cj   = lane & 3;        // H-column (within block) this lane gates
  const int gb0  = m * 16 + lg * 4; // first batch row this lane gates

  const float bias_f = bfp[j0 + cj];
  const float bias_i = bip[j0 + cj];
  const float bias_o = bop[j0 + cj];
  const float bias_g = bcp[j0 + cj];

  float creg[4] = {0.f, 0.f, 0.f, 0.f};  // c state in registers for all T steps

  const char* WlB   = reinterpret_cast<const char*>(Wl);
  const int colbase = lr * 4096;
  const int swz     = (lr & 7) << 4;

  // x-part GEMM for step t (off critical path)
  auto xpart = [&](int t, f32x4& a0, f32x4& a1) {
    a0 = f32x4{0.f, 0.f, 0.f, 0.f};
    a1 = f32x4{0.f, 0.f, 0.f, 0.f};
    const unsigned short* aptr = xb + (((long)(t * B_ + b)) << 10) + lg * 8;
    #pragma unroll
    for (int it = 0; it < 32; ++it) {
      short8b a  = *reinterpret_cast<const short8b*>(aptr + it * 32);
      short8b bb = *reinterpret_cast<const short8b*>(WlB + colbase + ((it * 64 + lg * 16) ^ swz));
      if (it & 1) a1 = __builtin_amdgcn_mfma_f32_16x16x32_bf16(a, bb, a1, 0, 0, 0);
      else        a0 = __builtin_amdgcn_mfma_f32_16x16x32_bf16(a, bb, a0, 0, 0, 0);
    }
  };

  f32x4 xa0, xa1;
  xpart(0, xa0, xa1);

  for (int t = 0; t < T_; ++t) {
    f32x4 a0 = xa0, a1 = xa1;

    if (t > 0) {
      // ---- poll all 512 per-wave flags for step t-1 (one shot per wave) ----
      const unsigned exp32 = MAGIC | (unsigned)(t - 1);
      const unsigned long long pat =
          ((unsigned long long)exp32 << 32) | (unsigned long long)exp32;
      const unsigned long long* fb =
          reinterpret_cast<const unsigned long long*>(flags + (long)(t - 1) * 512) + lane * 4;
      while (true) {
        unsigned long long f0 = ld64sys(fb);
        unsigned long long f1 = ld64sys(fb + 1);
        unsigned long long f2 = ld64sys(fb + 2);
        unsigned long long f3 = ld64sys(fb + 3);
        int ok = (f0 == pat) & (f1 == pat) & (f2 == pat) & (f3 == pat);
        if (__all(ok)) break;
      }
      asm volatile("" ::: "memory");  // no plain h loads above this line

      // ---- h-part GEMM: plain cached f32 reads of h_states[t-1] ----
      const float* basef = out + HLAST + ((long)(t - 1) * B_ + b) * H_ + lg * 8;
      float4 u0[8][2], u1[8][2];
      auto issue = [&](int g, float4 (&u)[8][2]) {
        #pragma unroll
        for (int f = 0; f < 8; ++f) {
          const float* p = basef + (g * 8 + f) * 32;
          u[f][0] = *reinterpret_cast<const float4*>(p);
          u[f][1] = *reinterpret_cast<const float4*>(p + 4);
        }
      };
      issue(0, u0);
      #pragma unroll
      for (int g = 0; g < 4; ++g) {          // static u0/u1 alternation
        float4 (&uc)[8][2] = (g & 1) ? u1 : u0;
        float4 (&un)[8][2] = (g & 1) ? u0 : u1;
        if (g < 3) issue(g + 1, un);
        #pragma unroll
        for (int f = 0; f < 8; ++f) {
          const int it = g * 8 + f;
          union { __hip_bfloat162 h2[4]; short8b v; } cv;
          cv.h2[0] = __float22bfloat162_rn(float2{uc[f][0].x, uc[f][0].y});
          cv.h2[1] = __float22bfloat162_rn(float2{uc[f][0].z, uc[f][0].w});
          cv.h2[2] = __float22bfloat162_rn(float2{uc[f][1].x, uc[f][1].y});
          cv.h2[3] = __float22bfloat162_rn(float2{uc[f][1].z, uc[f][1].w});
          short8b bb = *reinterpret_cast<const short8b*>(
              WlB + colbase + ((2048 + it * 64 + lg * 16) ^ swz));
          if (it & 1) a1 = __builtin_amdgcn_mfma_f32_16x16x32_bf16(cv.v, bb, a1, 0, 0, 0);
          else        a0 = __builtin_amdgcn_mfma_f32_16x16x32_bf16(cv.v, bb, a0, 0, 0, 0);
        }
      }
    }

    f32x4 acc = a0 + a1;

    // ---- gates: D[row=lg*4+r][col=lr]; lane wants cols g*4+cj ----
    float gate[4][4];
    #pragma unroll
    for (int g = 0; g < 4; ++g) {
      const int src = lg * 16 + g * 4 + cj;
      #pragma unroll
      for (int r = 0; r < 4; ++r) gate[g][r] = __shfl(acc[r], src, 64);
    }

    float hv[4];
    #pragma unroll
    for (int r = 0; r < 4; ++r) {
      float fg = sig_(gate[0][r] + bias_f);
      float ig = sig_(gate[1][r] + bias_i);
      float og = sig_(gate[2][r] + bias_o);
      float gg = tanh_(gate[3][r] + bias_g);
      float c  = fg * creg[r] + ig * gg;
      creg[r]  = c;
      hv[r]    = og * tanh_(c);
    }

    // ---- publish: h_states f32 store IS the publication (system-scope) ----
    if ((lane & 12) == 0) {
      #pragma unroll
      for (int r = 0; r < 4; ++r)
        __hip_atomic_store((unsigned*)&out[HLAST + ((long)t * B_ + gb0 + r) * H_ + j0 + cj],
                           __float_as_uint(hv[r]), __ATOMIC_RELAXED, SC_SYS);
    }
    if (t < T_ - 1) {
      asm volatile("s_waitcnt vmcnt(0)" ::: "memory");   // h stores landed at MALL
      if (lane == 0)
        __hip_atomic_store(&flags[(long)t * 512 + bid * 2 + m],
                           MAGIC | (unsigned)t, __ATOMIC_RELAXED, SC_SYS);
    }

    // ---- remaining outputs (plain stores) + next x-part (off critical path) ----
    if ((lane & 12) == 0) {
      #pragma unroll
      for (int r = 0; r < 4; ++r) {
        const int row  = gb0 + r;
        const int colj = j0 + cj;
        out[HLAST + TBH + ((long)t * B_ + row) * H_ + colj] = creg[r];
        if (t == T_ - 1) out[(long)row * H_ + colj] = hv[r];
      }
    }

    if (t + 1 < T_) xpart(t + 1, xa0, xa1);
  }
}

// Fallback (ws too small): per-step kernel gathering raw f32 each step.
__global__ void lstm_step_fallback_kernel(int t,
    const float* __restrict__ xf,
    const float* __restrict__ Wf, const float* __restrict__ Wi,
    const float* __restrict__ Wo, const float* __restrict__ Wc,
    const float* __restrict__ bfp, const float* __restrict__ bip,
    const float* __restrict__ bop, const float* __restrict__ bcp,
    float* __restrict__ out, unsigned short* __restrict__ hbuf)
{
  const int tid  = threadIdx.x;
  const int bid  = blockIdx.x;
  const int lane = tid & 63;
  const int m    = tid >> 6;
  const int lr   = lane & 15;
  const int lg   = lane >> 4;
  const int b    = m * 16 + lr;
  const int cj   = lane & 3;
  const int j0   = bid * 4;
  const int gb0  = m * 16 + lg * 4;

  const unsigned short* hcur = hbuf + (t & 1) * BH;
  f32x4 a0 = {0.f, 0.f, 0.f, 0.f};
  f32x4 a1 = {0.f, 0.f, 0.f, 0.f};

  const int g    = lr >> 2;
  const int colg = j0 + (lr & 3);
  const float* Wg = (g == 0) ? Wf : (g == 1) ? Wi : (g == 2) ? Wo : Wc;
  const float* axf = xf + ((long)b * T_ + t) * I_ + lg * 8;
  const unsigned short* ah = hcur + (b << 10) + lg * 8;
  #pragma unroll 4
  for (int it = 0; it < 32; ++it) {
    const int k0 = it * 32 + lg * 8;
    short8b a, bb;
    #pragma unroll
    for (int e = 0; e < 8; ++e) {
      a[e]  = (short)f2bf(axf[it * 32 + e]);
      bb[e] = (short)f2bf(Wg[(size_t)(k0 + e) * H_ + colg]);
    }
    if (it & 1) a1 = __builtin_amdgcn_mfma_f32_16x16x32_bf16(a, bb, a1, 0, 0, 0);
    else        a0 = __builtin_amdgcn_mfma_f32_16x16x32_bf16(a, bb, a0, 0, 0, 0);
  }
  #pragma unroll 4
  for (int it = 0; it < 32; ++it) {
    const int k0 = 1024 + it * 32 + lg * 8;
    short8b a = *reinterpret_cast<const short8b*>(ah + it * 32);
    short8b bb;
    #pragma unroll
    for (int e = 0; e < 8; ++e)
      bb[e] = (short)f2bf(Wg[(size_t)(k0 + e) * H_ + colg]);
    if (it & 1) a1 = __builtin_amdgcn_mfma_f32_16x16x32_bf16(a, bb, a1, 0, 0, 0);
    else        a0 = __builtin_amdgcn_mfma_f32_16x16x32_bf16(a, bb, a0, 0, 0, 0);
  }
  f32x4 acc = a0 + a1;

  float gate[4][4];
  #pragma unroll
  for (int gg = 0; gg < 4; ++gg) {
    const int src = lg * 16 + gg * 4 + cj;
    #pragma unroll
    for (int r = 0; r < 4; ++r) gate[gg][r] = __shfl(acc[r], src, 64);
  }

  if ((lane & 12) == 0) {
    const int col = j0 + cj;
    const float bias_f = bfp[col];
    const float bias_i = bip[col];
    const float bias_o = bop[col];
    const float bias_g = bcp[col];
    #pragma unroll
    for (int r = 0; r < 4; ++r) {
      const int row = gb0 + r;
      float cp = (t == 0) ? 0.f
               : out[HLAST + TBH + (long)((t - 1) * B_ + row) * H_ + col];
      float fg = sig_(gate[0][r] + bias_f);
      float ig = sig_(gate[1][r] + bias_i);
      float og = sig_(gate[2][r] + bias_o);
      float gv = tanh_(gate[3][r] + bias_g);
      float c  = fg * cp + ig * gv;
      float hv = og * tanh_(c);
      const long oh = (long)(t * B_ + row) * H_ + col;
      out[HLAST + oh]       = hv;
      out[HLAST + TBH + oh] = c;
      hbuf[((t + 1) & 1) * BH + row * H_ + col] = f2bf(hv);
      if (t == T_ - 1) out[(long)row * H_ + col] = hv;
    }
  }
}

extern "C" void kernel_launch(void* const* d_in, const int* in_sizes, int n_in,
                              void* d_out, int out_size, void* d_ws, size_t ws_size,
                              hipStream_t stream) {
  const float* x   = (const float*)d_in[0];
  const float* Wf  = (const float*)d_in[1];
  const float* bf_ = (const float*)d_in[2];
  const float* Wi  = (const float*)d_in[3];
  const float* bi_ = (const float*)d_in[4];
  const float* Wo  = (const float*)d_in[5];
  const float* bo_ = (const float*)d_in[6];
  const float* Wc  = (const float*)d_in[7];
  const float* bc_ = (const float*)d_in[8];
  float* out = (float*)d_out;

  const size_t xb_bytes    = (size_t)T_ * B_ * I_ * 2;      // 32 MiB
  const size_t flags_bytes = (size_t)T_ * 512 * 4;          // 1 MiB
  const bool fast = ws_size >= xb_bytes + flags_bytes;

  if (fast) {
    unsigned short* xb = (unsigned short*)d_ws;
    unsigned* flags    = (unsigned*)((char*)d_ws + xb_bytes);

    // flags must start != MAGIC|t each call (graph-replay safe); blit/SDMA
    // completion on the stream makes the zeros visible at the coherence point.
    (void)hipMemsetAsync(flags, 0, flags_bytes, stream);

    const int total_vec = T_ * B_ * I_ / 4;
    convert_x_kernel<<<dim3(total_vec / 256), dim3(256), 0, stream>>>(x, xb);

    lstm_kernel<<<dim3(NB), dim3(NTHR), 0, stream>>>(
        xb, Wf, Wi, Wo, Wc, bf_, bi_, bo_, bc_, out, flags);
  } else {
    unsigned short* hbuf = (unsigned short*)d_ws;
    (void)hipMemsetAsync(hbuf, 0, (size_t)2 * BH * 2, stream);
    for (int t = 0; t < T_; ++t)
      lstm_step_fallback_kernel<<<dim3(NB), dim3(NTHR), 0, stream>>>(
          t, x, Wf, Wi, Wo, Wc, bf_, bi_, bo_, bc_, out, hbuf);
  }
}

// Round 9
// 3696.902 us; speedup vs baseline: 1.7301x; 1.1036x over previous
//
#include <hip/hip_runtime.h>
#include <hip/hip_bf16.h>

typedef __attribute__((ext_vector_type(8))) short short8b;
typedef __attribute__((ext_vector_type(4))) float f32x4;

#define B_   32
#define T_   512
#define I_   1024
#define H_   1024
#define K_   2048          // I + H
#define NB   256           // blocks, each owns 4 H-cols (16 gate cols); 1 per CU
#define NTHR 128           // 2 waves: wave m handles batch rows m*16..m*16+15
#define BH   (B_ * H_)
#define HLAST (B_ * H_)
#define TBH ((long)T_ * B_ * H_)
#define SC_SYS __HIP_MEMORY_SCOPE_SYSTEM
#define MAGIC 0x5AB00000u   // flag value = MAGIC|t; != 0 (memset) and != 0xAAAAAAAA (poison)

__device__ __forceinline__ unsigned short f2bf(float f) {
  union { float f; unsigned u; } c; c.f = f;
  unsigned r = (c.u + 0x7FFFu + ((c.u >> 16) & 1u)) >> 16;  // RNE
  return (unsigned short)r;
}

__device__ __forceinline__ float sig_(float x)  { return 1.0f / (1.0f + __expf(-x)); }
__device__ __forceinline__ float tanh_(float x) { return 1.0f - 2.0f / (__expf(2.0f * x) + 1.0f); }

__device__ __forceinline__ unsigned long long ld64sys(const void* p) {
  return __hip_atomic_load((const unsigned long long*)p, __ATOMIC_RELAXED, SC_SYS);
}

// x [B][T][I] f32  ->  xb [T][B][I] bf16 (step-t slab contiguous)
__global__ void convert_x_kernel(const float* __restrict__ x, unsigned short* __restrict__ xb) {
  long vid = (long)blockIdx.x * blockDim.x + threadIdx.x;
  long o = vid * 4;
  if (o >= (long)T_ * B_ * I_) return;
  int i  = (int)(o & (I_ - 1));
  long bt = o >> 10;
  int b  = (int)(bt & (B_ - 1));
  int t  = (int)(bt >> 5);
  float4 v = *reinterpret_cast<const float4*>(x + (((long)b * T_ + t) << 10) + i);
  ushort4 pk;
  pk.x = f2bf(v.x); pk.y = f2bf(v.y); pk.z = f2bf(v.z); pk.w = f2bf(v.w);
  *reinterpret_cast<ushort4*>(xb + o) = pk;
}

// Persistent LSTM, plain launch (256 blocks x 128 thr, 64 KiB LDS -> 1/CU).
// Publish: hseq bf16 system stores -> vmcnt(0) -> syncthreads -> ONE per-block
// flag (tid0, system). Consume: wave 0 polls all 256 flags with 2x8B system
// loads per lane (one round trip), syncthreads, then PLAIN CACHED bf16 loads
// of hseq (write-once addresses; start-of-kernel agent-acquire fence purges
// pre-kernel residue -- mechanism validated by round 8's passing run).
// HB16=false: no hseq slab; h_states f32 output doubles as the synced payload.
template <bool HB16>
__global__ __launch_bounds__(NTHR, 1)
void lstm_kernel(const unsigned short* __restrict__ xb,
                 const float* __restrict__ Wf, const float* __restrict__ Wi,
                 const float* __restrict__ Wo, const float* __restrict__ Wc,
                 const float* __restrict__ bfp, const float* __restrict__ bip,
                 const float* __restrict__ bop, const float* __restrict__ bcp,
                 float* __restrict__ out, unsigned short* __restrict__ hseq,
                 unsigned* __restrict__ flags)
{
  __shared__ unsigned short Wl[16 * 2048];  // 64 KiB weight stripe (bf16, swizzled)
  const int tid = threadIdx.x;
  const int bid = blockIdx.x;
  const int j0  = bid * 4;

  {
    const float* Wg[4] = {Wf, Wi, Wo, Wc};
    for (int g = 0; g < 4; ++g) {
      const float* Wp = Wg[g] + j0;
      for (int k = tid; k < K_; k += NTHR) {
        float4 w = *reinterpret_cast<const float4*>(Wp + (long)k * H_);
        float wv[4] = {w.x, w.y, w.z, w.w};
        #pragma unroll
        for (int cj = 0; cj < 4; ++cj) {
          int n = g * 4 + cj;
          int byteoff = n * 4096 + ((2 * k) ^ ((n & 7) << 4));
          *reinterpret_cast<unsigned short*>(reinterpret_cast<char*>(Wl) + byteoff) = f2bf(wv[cj]);
        }
      }
    }
  }
  __syncthreads();

  // One-time purge of pre-kernel L1/L2 residue (poison/memset). After this,
  // lines enter this XCD's caches only via our own post-flag reads.
  __builtin_amdgcn_fence(__ATOMIC_ACQUIRE, "agent");

  const int lane = tid & 63;
  const int m    = tid >> 6;
  const int lr   = lane & 15;
  const int lg   = lane >> 4;
  const int b    = m * 16 + lr;     // batch row fed into A-fragment
  const int cj   = lane & 3;        // H-column (within block) this lane gates
  const int gb0  = m * 16 + lg * 4; // first batch row this lane gates

  const float bias_f = bfp[j0 + cj];
  const float bias_i = bip[j0 + cj];
  const float bias_o = bop[j0 + cj];
  const float bias_g = bcp[j0 + cj];

  float creg[4] = {0.f, 0.f, 0.f, 0.f};  // c state in registers for all T steps

  const char* WlB   = reinterpret_cast<const char*>(Wl);
  const int colbase = lr * 4096;
  const int swz     = (lr & 7) << 4;

  // x-part GEMM for step t (runs in the rendezvous shadow)
  auto xpart = [&](int t, f32x4& a0, f32x4& a1) {
    a0 = f32x4{0.f, 0.f, 0.f, 0.f};
    a1 = f32x4{0.f, 0.f, 0.f, 0.f};
    const unsigned short* aptr = xb + (((long)(t * B_ + b)) << 10) + lg * 8;
    #pragma unroll
    for (int it = 0; it < 32; ++it) {
      short8b a  = *reinterpret_cast<const short8b*>(aptr + it * 32);
      short8b bb = *reinterpret_cast<const short8b*>(WlB + colbase + ((it * 64 + lg * 16) ^ swz));
      if (it & 1) a1 = __builtin_amdgcn_mfma_f32_16x16x32_bf16(a, bb, a1, 0, 0, 0);
      else        a0 = __builtin_amdgcn_mfma_f32_16x16x32_bf16(a, bb, a0, 0, 0, 0);
    }
  };

  f32x4 xa0, xa1;
  xpart(0, xa0, xa1);

  for (int t = 0; t < T_; ++t) {
    f32x4 a0 = xa0, a1 = xa1;

    if (t > 0) {
      // ---- rendezvous: wave 0 polls 256 per-block flags (one RT per iter) ----
      if (m == 0) {
        const unsigned exp32 = MAGIC | (unsigned)(t - 1);
        const unsigned long long pat =
            ((unsigned long long)exp32 << 32) | (unsigned long long)exp32;
        const unsigned long long* fb =
            reinterpret_cast<const unsigned long long*>(flags + (long)(t - 1) * NB) + lane * 2;
        while (true) {
          unsigned long long f0 = ld64sys(fb);
          unsigned long long f1 = ld64sys(fb + 1);
          if (__all((f0 == pat) & (f1 == pat))) break;
        }
      }
      __syncthreads();                 // releases wave 1; orders loads below
      asm volatile("" ::: "memory");   // no h loads hoisted above this line

      if (HB16) {
        // ---- h-part GEMM: plain cached bf16 loads of hseq[t-1] ----
        const unsigned short* base = hseq + (long)(t - 1) * BH + (b << 10) + lg * 8;
        short8b u0[8], u1[8];
        auto issue = [&](int g, short8b (&u)[8]) {
          #pragma unroll
          for (int f = 0; f < 8; ++f)
            u[f] = *reinterpret_cast<const short8b*>(base + (g * 8 + f) * 32);
        };
        issue(0, u0);
        #pragma unroll
        for (int g = 0; g < 4; ++g) {          // static u0/u1 alternation
          short8b (&uc)[8] = (g & 1) ? u1 : u0;
          short8b (&un)[8] = (g & 1) ? u0 : u1;
          if (g < 3) issue(g + 1, un);
          #pragma unroll
          for (int f = 0; f < 8; ++f) {
            const int it = g * 8 + f;
            short8b bb = *reinterpret_cast<const short8b*>(
                WlB + colbase + ((2048 + it * 64 + lg * 16) ^ swz));
            if (it & 1) a1 = __builtin_amdgcn_mfma_f32_16x16x32_bf16(uc[f], bb, a1, 0, 0, 0);
            else        a0 = __builtin_amdgcn_mfma_f32_16x16x32_bf16(uc[f], bb, a0, 0, 0, 0);
          }
        }
      } else {
        // ---- h-part GEMM: plain cached f32 loads of h_states[t-1] ----
        const float* basef = out + HLAST + ((long)(t - 1) * B_ + b) * H_ + lg * 8;
        float4 u0[8][2], u1[8][2];
        auto issue = [&](int g, float4 (&u)[8][2]) {
          #pragma unroll
          for (int f = 0; f < 8; ++f) {
            const float* p = basef + (g * 8 + f) * 32;
            u[f][0] = *reinterpret_cast<const float4*>(p);
            u[f][1] = *reinterpret_cast<const float4*>(p + 4);
          }
        };
        issue(0, u0);
        #pragma unroll
        for (int g = 0; g < 4; ++g) {
          float4 (&uc)[8][2] = (g & 1) ? u1 : u0;
          float4 (&un)[8][2] = (g & 1) ? u0 : u1;
          if (g < 3) issue(g + 1, un);
          #pragma unroll
          for (int f = 0; f < 8; ++f) {
            const int it = g * 8 + f;
            union { __hip_bfloat162 h2[4]; short8b v; } cv;
            cv.h2[0] = __float22bfloat162_rn(float2{uc[f][0].x, uc[f][0].y});
            cv.h2[1] = __float22bfloat162_rn(float2{uc[f][0].z, uc[f][0].w});
            cv.h2[2] = __float22bfloat162_rn(float2{uc[f][1].x, uc[f][1].y});
            cv.h2[3] = __float22bfloat162_rn(float2{uc[f][1].z, uc[f][1].w});
            short8b bb = *reinterpret_cast<const short8b*>(
                WlB + colbase + ((2048 + it * 64 + lg * 16) ^ swz));
            if (it & 1) a1 = __builtin_amdgcn_mfma_f32_16x16x32_bf16(cv.v, bb, a1, 0, 0, 0);
            else        a0 = __builtin_amdgcn_mfma_f32_16x16x32_bf16(cv.v, bb, a0, 0, 0, 0);
          }
        }
      }
    }

    f32x4 acc = a0 + a1;

    // ---- gates: D[row=lg*4+r][col=lr]; lane wants cols g*4+cj ----
    float gate[4][4];
    #pragma unroll
    for (int g = 0; g < 4; ++g) {
      const int src = lg * 16 + g * 4 + cj;
      #pragma unroll
      for (int r = 0; r < 4; ++r) gate[g][r] = __shfl(acc[r], src, 64);
    }

    float hv[4];
    #pragma unroll
    for (int r = 0; r < 4; ++r) {
      float fg = sig_(gate[0][r] + bias_f);
      float ig = sig_(gate[1][r] + bias_i);
      float og = sig_(gate[2][r] + bias_o);
      float gg = tanh_(gate[3][r] + bias_g);
      float c  = fg * creg[r] + ig * gg;
      creg[r]  = c;
      hv[r]    = og * tanh_(c);
    }

    // ---- publish h[t] -> ack -> single per-block flag ----
    if (t < T_ - 1) {
      if (HB16) {
        unsigned hw[4];
        #pragma unroll
        for (int r = 0; r < 4; ++r) {
          unsigned mine  = f2bf(hv[r]);
          unsigned other = (unsigned)__shfl((int)mine, lane ^ 1, 64);
          hw[r] = mine | (other << 16);            // valid on even-cj writer lanes
        }
        if ((lane & 12) == 0 && (cj & 1) == 0) {
          unsigned short* hp = hseq + (long)t * BH;
          #pragma unroll
          for (int r = 0; r < 4; ++r)
            __hip_atomic_store((unsigned*)(hp + (gb0 + r) * H_ + j0 + cj), hw[r],
                               __ATOMIC_RELAXED, SC_SYS);
        }
      } else {
        if ((lane & 12) == 0) {
          #pragma unroll
          for (int r = 0; r < 4; ++r)
            __hip_atomic_store((unsigned*)&out[HLAST + ((long)t * B_ + gb0 + r) * H_ + j0 + cj],
                               __float_as_uint(hv[r]), __ATOMIC_RELAXED, SC_SYS);
        }
      }
      asm volatile("s_waitcnt vmcnt(0)" ::: "memory");   // stores landed at MALL
      __syncthreads();                                    // both waves acked
      if (tid == 0)
        __hip_atomic_store(&flags[(long)t * NB + bid], MAGIC | (unsigned)t,
                           __ATOMIC_RELAXED, SC_SYS);
    }

    // ---- plain output stores + next x-part (rendezvous shadow) ----
    if ((lane & 12) == 0) {
      #pragma unroll
      for (int r = 0; r < 4; ++r) {
        const int row  = gb0 + r;
        const int colj = j0 + cj;
        const long oh  = (long)(t * B_ + row) * H_ + colj;
        if (HB16 || t == T_ - 1) out[HLAST + oh] = hv[r];  // !HB16 stored above
        out[HLAST + TBH + oh] = creg[r];
        if (t == T_ - 1) out[(long)row * H_ + colj] = hv[r];
      }
    }

    if (t + 1 < T_) xpart(t + 1, xa0, xa1);
  }
}

// Fallback (ws too small): per-step kernel gathering raw f32 each step.
__global__ void lstm_step_fallback_kernel(int t,
    const float* __restrict__ xf,
    const float* __restrict__ Wf, const float* __restrict__ Wi,
    const float* __restrict__ Wo, const float* __restrict__ Wc,
    const float* __restrict__ bfp, const float* __restrict__ bip,
    const float* __restrict__ bop, const float* __restrict__ bcp,
    float* __restrict__ out, unsigned short* __restrict__ hbuf)
{
  const int tid  = threadIdx.x;
  const int bid  = blockIdx.x;
  const int lane = tid & 63;
  const int m    = tid >> 6;
  const int lr   = lane & 15;
  const int lg   = lane >> 4;
  const int b    = m * 16 + lr;
  const int cj   = lane & 3;
  const int j0   = bid * 4;
  const int gb0  = m * 16 + lg * 4;

  const unsigned short* hcur = hbuf + (t & 1) * BH;
  f32x4 a0 = {0.f, 0.f, 0.f, 0.f};
  f32x4 a1 = {0.f, 0.f, 0.f, 0.f};

  const int g    = lr >> 2;
  const int colg = j0 + (lr & 3);
  const float* Wg = (g == 0) ? Wf : (g == 1) ? Wi : (g == 2) ? Wo : Wc;
  const float* axf = xf + ((long)b * T_ + t) * I_ + lg * 8;
  const unsigned short* ah = hcur + (b << 10) + lg * 8;
  #pragma unroll 4
  for (int it = 0; it < 32; ++it) {
    const int k0 = it * 32 + lg * 8;
    short8b a, bb;
    #pragma unroll
    for (int e = 0; e < 8; ++e) {
      a[e]  = (short)f2bf(axf[it * 32 + e]);
      bb[e] = (short)f2bf(Wg[(size_t)(k0 + e) * H_ + colg]);
    }
    if (it & 1) a1 = __builtin_amdgcn_mfma_f32_16x16x32_bf16(a, bb, a1, 0, 0, 0);
    else        a0 = __builtin_amdgcn_mfma_f32_16x16x32_bf16(a, bb, a0, 0, 0, 0);
  }
  #pragma unroll 4
  for (int it = 0; it < 32; ++it) {
    const int k0 = 1024 + it * 32 + lg * 8;
    short8b a = *reinterpret_cast<const short8b*>(ah + it * 32);
    short8b bb;
    #pragma unroll
    for (int e = 0; e < 8; ++e)
      bb[e] = (short)f2bf(Wg[(size_t)(k0 + e) * H_ + colg]);
    if (it & 1) a1 = __builtin_amdgcn_mfma_f32_16x16x32_bf16(a, bb, a1, 0, 0, 0);
    else        a0 = __builtin_amdgcn_mfma_f32_16x16x32_bf16(a, bb, a0, 0, 0, 0);
  }
  f32x4 acc = a0 + a1;

  float gate[4][4];
  #pragma unroll
  for (int gg = 0; gg < 4; ++gg) {
    const int src = lg * 16 + gg * 4 + cj;
    #pragma unroll
    for (int r = 0; r < 4; ++r) gate[gg][r] = __shfl(acc[r], src, 64);
  }

  if ((lane & 12) == 0) {
    const int col = j0 + cj;
    const float bias_f = bfp[col];
    const float bias_i = bip[col];
    const float bias_o = bop[col];
    const float bias_g = bcp[col];
    #pragma unroll
    for (int r = 0; r < 4; ++r) {
      const int row = gb0 + r;
      float cp = (t == 0) ? 0.f
               : out[HLAST + TBH + (long)((t - 1) * B_ + row) * H_ + col];
      float fg = sig_(gate[0][r] + bias_f);
      float ig = sig_(gate[1][r] + bias_i);
      float og = sig_(gate[2][r] + bias_o);
      float gv = tanh_(gate[3][r] + bias_g);
      float c  = fg * cp + ig * gv;
      float hv = og * tanh_(c);
      const long oh = (long)(t * B_ + row) * H_ + col;
      out[HLAST + oh]       = hv;
      out[HLAST + TBH + oh] = c;
      hbuf[((t + 1) & 1) * BH + row * H_ + col] = f2bf(hv);
      if (t == T_ - 1) out[(long)row * H_ + col] = hv;
    }
  }
}

extern "C" void kernel_launch(void* const* d_in, const int* in_sizes, int n_in,
                              void* d_out, int out_size, void* d_ws, size_t ws_size,
                              hipStream_t stream) {
  const float* x   = (const float*)d_in[0];
  const float* Wf  = (const float*)d_in[1];
  const float* bf_ = (const float*)d_in[2];
  const float* Wi  = (const float*)d_in[3];
  const float* bi_ = (const float*)d_in[4];
  const float* Wo  = (const float*)d_in[5];
  const float* bo_ = (const float*)d_in[6];
  const float* Wc  = (const float*)d_in[7];
  const float* bc_ = (const float*)d_in[8];
  float* out = (float*)d_out;

  const size_t xb_bytes    = (size_t)T_ * B_ * I_ * 2;      // 32 MiB
  const size_t hseq_bytes  = (size_t)T_ * BH * 2;           // 32 MiB
  const size_t flags_bytes = (size_t)T_ * NB * 4;           // 512 KiB

  const bool has_xb   = ws_size >= xb_bytes + flags_bytes;
  const bool has_hseq = ws_size >= xb_bytes + hseq_bytes + flags_bytes;

  if (has_xb) {
    unsigned short* xb   = (unsigned short*)d_ws;
    unsigned short* hseq = has_hseq ? (unsigned short*)((char*)d_ws + xb_bytes) : nullptr;
    unsigned* flags = (unsigned*)((char*)d_ws + (has_hseq ? xb_bytes + hseq_bytes : xb_bytes));

    // flags must start != MAGIC|t each call (graph-replay safe)
    (void)hipMemsetAsync(flags, 0, flags_bytes, stream);

    const int total_vec = T_ * B_ * I_ / 4;
    convert_x_kernel<<<dim3(total_vec / 256), dim3(256), 0, stream>>>(x, xb);

    if (has_hseq)
      lstm_kernel<true><<<dim3(NB), dim3(NTHR), 0, stream>>>(
          xb, Wf, Wi, Wo, Wc, bf_, bi_, bo_, bc_, out, hseq, flags);
    else
      lstm_kernel<false><<<dim3(NB), dim3(NTHR), 0, stream>>>(
          xb, Wf, Wi, Wo, Wc, bf_, bi_, bo_, bc_, out, hseq, flags);
  } else {
    unsigned short* hbuf = (unsigned short*)d_ws;
    (void)hipMemsetAsync(hbuf, 0, (size_t)2 * BH * 2, stream);
    for (int t = 0; t < T_; ++t)
      lstm_step_fallback_kernel<<<dim3(NB), dim3(NTHR), 0, stream>>>(
          t, x, Wf, Wi, Wo, Wc, bf_, bi_, bo_, bc_, out, hbuf);
  }
}